// Round 9
// baseline (291.702 us; speedup 1.0000x reference)
//
#include <hip/hip_runtime.h>
#include <math.h>

#define NP 125
#define NC 21
#define THRESH 0.3f

// ---------- A: streaming LSE, copy-kernel staging pattern ----------
// block = 256 threads = 256 consecutive priors = 5376 floats = 1344 float4.
__global__ void __launch_bounds__(256) mbloss_lse(
    const float* __restrict__ scores, const float* __restrict__ target,
    float2* __restrict__ conf2) {

    __shared__ float s[256 * NC];            // 21504 B -> 7 blocks/CU (28 waves)

    const int tid = threadIdx.x;
    const size_t fbase = (size_t)blockIdx.x * (256 * NC);   // float offset, 16B-aligned

    // dense dwordx4 loads (the 6.3 TB/s copy pattern), then ds_write_b128
    const float4* g4 = (const float4*)(scores + fbase);
    float4* s4 = (float4*)s;
    float4 t0 = g4[tid];
    float4 t1 = g4[256 + tid];
    float4 t2 = g4[512 + tid];
    float4 t3 = g4[768 + tid];
    float4 t4 = g4[1024 + tid];
    float4 t5;
    const bool extra = tid < 64;
    if (extra) t5 = g4[1280 + tid];
    s4[tid] = t0;
    s4[256 + tid] = t1;
    s4[512 + tid] = t2;
    s4[768 + tid] = t3;
    s4[1024 + tid] = t4;
    if (extra) s4[1280 + tid] = t5;

    // overlap: per-thread row/label (tiny, L2/LLC-resident)
    const int idx = blockIdx.x * 256 + tid;   // global prior index
    const int row = idx / NP;
    const int lbl = (int)target[(size_t)row * 8 + 7];

    __syncthreads();

    const float* p = s + tid * NC;            // stride 21 (odd) -> free 2-way alias
    float m = p[0];
#pragma unroll
    for (int c = 1; c < NC; ++c) m = fmaxf(m, p[c]);
    float ss = 0.f;
#pragma unroll
    for (int c = 0; c < NC; ++c) ss += __expf(p[c] - m);
    const float lse = m + __logf(ss);

    conf2[idx] = make_float2(lse - p[lbl], lse - p[0]);   // (pos-variant, neg-variant)
}

// ---------- B: per-row match/sort/reduce; wave per row, no LDS ----------
#define BWAVES 2048
__global__ void __launch_bounds__(256) mbloss_row(
    const float* __restrict__ locs, const float* __restrict__ target,
    const float* __restrict__ priors, const float2* __restrict__ conf2,
    float4* __restrict__ partials, int batch) {

    const int tid  = threadIdx.x;
    const int wave = tid >> 6;
    const int lane = tid & 63;
    const int gw   = blockIdx.x * 4 + wave;      // global wave id [0, BWAVES)

    const int  p1 = lane + 64;
    const bool v1 = (p1 < NP);
    const float4* pr4 = (const float4*)priors;
    float4 P0 = pr4[lane];
    float4 P1 = v1 ? pr4[p1] : make_float4(0.f, 0.f, 1.f, 1.f);

    float acc_conf = 0.f, acc_sl1 = 0.f, acc_ang = 0.f, acc_np = 0.f;

    for (int r = gw; r < batch; r += BWAVES) {
        const float* t = target + (size_t)r * 8;
        const float bx = t[0], by = t[1], bw = t[2], bh = t[3];
        const float sa = t[5], ca = t[6];

        float iou0, iou1 = -1.f;
        {
            float iw = fminf(bx + bw * 0.5f, P0.x + P0.z * 0.5f) -
                       fmaxf(bx - bw * 0.5f, P0.x - P0.z * 0.5f);
            float ih = fminf(by + bh * 0.5f, P0.y + P0.w * 0.5f) -
                       fmaxf(by - bh * 0.5f, P0.y - P0.w * 0.5f);
            iw = fmaxf(iw, 0.f); ih = fmaxf(ih, 0.f);
            float inter = iw * ih;
            iou0 = inter / (bw * bh + P0.z * P0.w - inter);
        }
        if (v1) {
            float iw = fminf(bx + bw * 0.5f, P1.x + P1.z * 0.5f) -
                       fmaxf(bx - bw * 0.5f, P1.x - P1.z * 0.5f);
            float ih = fminf(by + bh * 0.5f, P1.y + P1.w * 0.5f) -
                       fmaxf(by - bh * 0.5f, P1.y - P1.w * 0.5f);
            iw = fmaxf(iw, 0.f); ih = fmaxf(ih, 0.f);
            float inter = iw * ih;
            iou1 = inter / (bw * bh + P1.z * P1.w - inter);
        }

        // coalesced conf loads (issue early; independent of argmax)
        float2 c0 = conf2[(size_t)r * NP + lane];
        float2 c1 = v1 ? conf2[(size_t)r * NP + p1] : make_float2(0.f, -1.f);

        // argmax, first-index tie-break, butterfly (all lanes agree)
        float bv = iou0; int bi = lane;
        if (iou1 > bv) { bv = iou1; bi = p1; }
#pragma unroll
        for (int off = 1; off < 64; off <<= 1) {
            float vo = __shfl_xor(bv, off, 64);
            int   io = __shfl_xor(bi, off, 64);
            if (vo > bv || (vo == bv && io < bi)) { bv = vo; bi = io; }
        }
        const int best = bi;

        const bool pos0 = (lane == best) || (iou0 >= THRESH);
        const bool pos1 = v1 && ((p1 == best) || (iou1 >= THRESH));
        const int npos = __popcll(__ballot(pos0)) + __popcll(__ballot(pos1));
        acc_np += (pos0 ? 1.f : 0.f) + (pos1 ? 1.f : 0.f);

#define SL1(d) (fabsf(d) < 1.f ? 0.5f * (d) * (d) : fabsf(d) - 0.5f)
        if (pos0) {
            acc_conf += c0.x;
            const float* L = locs + (size_t)r * (NP * 6) + lane * 6;
            float g0 = (bx - P0.x) / (P0.z * 0.1f);
            float g1 = (by - P0.y) / (P0.w * 0.1f);
            float g2 = __logf(bw / P0.z) * 5.f;
            float g3 = __logf(bh / P0.w) * 5.f;
            float d0 = L[0] - g0, d1 = L[1] - g1, d2 = L[2] - g2, d3 = L[3] - g3;
            acc_sl1 += SL1(d0) + SL1(d1) + SL1(d2) + SL1(d3);
            float a0 = L[4] - sa, a1 = L[5] - ca;
            acc_ang += a0 * a0 + a1 * a1;
        }
        if (pos1) {
            acc_conf += c1.x;
            const float* L = locs + (size_t)r * (NP * 6) + p1 * 6;
            float g0 = (bx - P1.x) / (P1.z * 0.1f);
            float g1 = (by - P1.y) / (P1.w * 0.1f);
            float g2 = __logf(bw / P1.z) * 5.f;
            float g3 = __logf(bh / P1.w) * 5.f;
            float d0 = L[0] - g0, d1 = L[1] - g1, d2 = L[2] - g2, d3 = L[3] - g3;
            acc_sl1 += SL1(d0) + SL1(d1) + SL1(d2) + SL1(d3);
            float a0 = L[4] - sa, a1 = L[5] - ca;
            acc_ang += a0 * a0 + a1 * a1;
        }

        // register bitonic sort of conf_neg (128 virtual elems, descending)
        float x0 = pos0 ? 0.f : c0.y;                  // conf_neg >= 0 always
        float x1 = v1 ? (pos1 ? 0.f : c1.y) : -1.f;    // pads sort last
#pragma unroll
        for (int k = 2; k <= 128; k <<= 1) {
#pragma unroll
            for (int j = k >> 1; j >= 1; j >>= 1) {
                if (j == 64) {
                    float a = fmaxf(x0, x1), b = fminf(x0, x1);
                    x0 = a; x1 = b;
                } else {
                    bool lower = (lane & j) == 0;
                    bool d0 = ((lane & k) == 0);
                    bool d1 = (((lane + 64) & k) == 0);
                    float o0 = __shfl_xor(x0, j, 64);
                    float o1 = __shfl_xor(x1, j, 64);
                    x0 = (lower == d0) ? fmaxf(x0, o0) : fminf(x0, o0);
                    x1 = (lower == d1) ? fmaxf(x1, o1) : fminf(x1, o1);
                }
            }
        }

        int kk = 3 * npos; if (kk > NP) kk = NP;
        acc_conf += (lane < kk ? x0 : 0.f) + (lane + 64 < kk ? x1 : 0.f);
    }

    // wave reduce, one float4 store per wave
#pragma unroll
    for (int off = 1; off < 64; off <<= 1) {
        acc_conf += __shfl_xor(acc_conf, off, 64);
        acc_sl1  += __shfl_xor(acc_sl1,  off, 64);
        acc_ang  += __shfl_xor(acc_ang,  off, 64);
        acc_np   += __shfl_xor(acc_np,   off, 64);
    }
    if (lane == 0) partials[gw] = make_float4(acc_conf, acc_sl1, acc_ang, acc_np);
}

// ---------- fin: reduce 2048 partials ----------
__global__ void __launch_bounds__(1024) mbloss_fin(const float4* __restrict__ partials,
                                                   int n, float* __restrict__ out) {
    __shared__ float4 red[1024];
    const int tid = threadIdx.x;
    float4 a = make_float4(0.f, 0.f, 0.f, 0.f);
    for (int i = tid; i < n; i += 1024) {
        float4 p = partials[i];
        a.x += p.x; a.y += p.y; a.z += p.z; a.w += p.w;
    }
    red[tid] = a;
    __syncthreads();
    for (int s = 512; s > 0; s >>= 1) {
        if (tid < s) {
            red[tid].x += red[tid + s].x; red[tid].y += red[tid + s].y;
            red[tid].z += red[tid + s].z; red[tid].w += red[tid + s].w;
        }
        __syncthreads();
    }
    if (tid == 0) {
        float npt  = red[0].w;
        float conf = red[0].x / npt;
        float loc  = red[0].y / (npt * 4.f);
        float ang  = 25.f * red[0].z / (npt * 2.f);
        out[0] = conf; out[1] = loc; out[2] = ang; out[3] = conf + loc + ang;
    }
}

extern "C" void kernel_launch(void* const* d_in, const int* in_sizes, int n_in,
                              void* d_out, int out_size, void* d_ws, size_t ws_size,
                              hipStream_t stream) {
    const float* locs   = (const float*)d_in[0];
    const float* scores = (const float*)d_in[1];
    const float* target = (const float*)d_in[2];
    const float* priors = (const float*)d_in[3];
    float* out = (float*)d_out;

    const int batch = in_sizes[2] / 8;        // target is (B,1,8); 16384
    const int npri  = batch * NP;             // 2,048,000 (divisible by 256)

    float2* conf2    = (float2*)d_ws;                              // 16 MB
    float4* partials = (float4*)((char*)d_ws + (size_t)npri * 8);  // 32 KB

    mbloss_lse<<<npri / 256, 256, 0, stream>>>(scores, target, conf2);
    mbloss_row<<<BWAVES / 4, 256, 0, stream>>>(locs, target, priors, conf2,
                                               partials, batch);
    mbloss_fin<<<1, 1024, 0, stream>>>(partials, BWAVES, out);
}

// Round 10
// 276.646 us; speedup vs baseline: 1.0544x; 1.0544x over previous
//
#include <hip/hip_runtime.h>
#include <math.h>

#define NP 125
#define NC 21
#define ROWF (NP * NC)        // 2625 floats = 10500 B per score row
#define THRESH 0.3f

// async global->LDS (gfx950). LDS dest layout = wave-uniform base + lane*size.
__device__ inline void ald16(const float* g, float* l) {
    __builtin_amdgcn_global_load_lds(
        (const __attribute__((address_space(1))) void*)g,
        (__attribute__((address_space(3))) void*)l, 16, 0, 0);
}
__device__ inline void ald4(const float* g, float* l) {
    __builtin_amdgcn_global_load_lds(
        (const __attribute__((address_space(1))) void*)g,
        (__attribute__((address_space(3))) void*)l, 4, 0, 0);
}

// vmcnt-only waits: lgkmcnt=0xF (bits 11:8), expcnt=7 (bits 6:4), vmcnt low bits 3:0
#define WAIT_VM11() do { __builtin_amdgcn_s_waitcnt(0xF7B); __builtin_amdgcn_sched_barrier(0); } while (0)
#define WAIT_VM0()  do { __builtin_amdgcn_s_waitcnt(0xF70); __builtin_amdgcn_sched_barrier(0); } while (0)

struct RowM {
    float bx, by, bw, bh, sa, ca;
    int   lbl, npos;
    bool  pos0, pos1;
};

// IoU + argmax (first-index tie-break) + pos mask; needs only priors/target.
__device__ inline void match_row(const float* t, const float4& P0, const float4& P1,
                                 int lane, int p1, bool v1, RowM& R) {
    R.bx = t[0]; R.by = t[1]; R.bw = t[2]; R.bh = t[3];
    R.sa = t[5]; R.ca = t[6]; R.lbl = (int)t[7];

    float iou0, iou1 = -1.f;
    {
        float iw = fminf(R.bx + R.bw * 0.5f, P0.x + P0.z * 0.5f) -
                   fmaxf(R.bx - R.bw * 0.5f, P0.x - P0.z * 0.5f);
        float ih = fminf(R.by + R.bh * 0.5f, P0.y + P0.w * 0.5f) -
                   fmaxf(R.by - R.bh * 0.5f, P0.y - P0.w * 0.5f);
        iw = fmaxf(iw, 0.f); ih = fmaxf(ih, 0.f);
        float inter = iw * ih;
        iou0 = inter / (R.bw * R.bh + P0.z * P0.w - inter);
    }
    if (v1) {
        float iw = fminf(R.bx + R.bw * 0.5f, P1.x + P1.z * 0.5f) -
                   fmaxf(R.bx - R.bw * 0.5f, P1.x - P1.z * 0.5f);
        float ih = fminf(R.by + R.bh * 0.5f, P1.y + P1.w * 0.5f) -
                   fmaxf(R.by - R.bh * 0.5f, P1.y - P1.w * 0.5f);
        iw = fmaxf(iw, 0.f); ih = fmaxf(ih, 0.f);
        float inter = iw * ih;
        iou1 = inter / (R.bw * R.bh + P1.z * P1.w - inter);
    }

    float bv = iou0; int bi = lane;
    if (iou1 > bv) { bv = iou1; bi = p1; }
#pragma unroll
    for (int off = 1; off < 64; off <<= 1) {
        float vo = __shfl_xor(bv, off, 64);
        int   io = __shfl_xor(bi, off, 64);
        if (vo > bv || (vo == bv && io < bi)) { bv = vo; bi = io; }
    }
    R.pos0 = (lane == bi) || (iou0 >= THRESH);
    R.pos1 = v1 && ((p1 == bi) || (iou1 >= THRESH));
    R.npos = __popcll(__ballot(R.pos0)) + __popcll(__ballot(R.pos1));
}

// LSE + conf for both priors of this lane, from a staged LDS row.
// e2624 patches the one float not staged (prior 124, class 20).
__device__ inline void lse_row(const float* srow, float e2624, int lane, int p1,
                               bool v1, int sel0, int sel1,
                               float& conf0, float& conf1) {
    {
        const float* s0 = srow + lane * NC;
        float m = s0[0];
#pragma unroll
        for (int c = 1; c < NC; ++c) m = fmaxf(m, s0[c]);
        float ss = 0.f, pick = 0.f;
#pragma unroll
        for (int c = 0; c < NC; ++c) {
            ss += __expf(s0[c] - m);
            pick += (c == sel0) ? s0[c] : 0.f;
        }
        conf0 = (m + __logf(ss)) - pick;
    }
    conf1 = 0.f;
    if (v1) {
        const float* s1 = srow + p1 * NC;
        const bool last = (p1 == NP - 1);
        float m = -1e30f, ss = 0.f, pick = 0.f;
#pragma unroll
        for (int c = 0; c < NC; ++c) {
            float val = (last && c == NC - 1) ? e2624 : s1[c];
            m = fmaxf(m, val);
        }
#pragma unroll
        for (int c = 0; c < NC; ++c) {
            float val = (last && c == NC - 1) ? e2624 : s1[c];
            ss += __expf(val - m);
            pick += (c == sel1) ? val : 0.f;
        }
        conf1 = (m + __logf(ss)) - pick;
    }
}

// register bitonic sort (128 virtual elems desc) + top-kk sum
__device__ inline float topk_sum(float x0, float x1, int lane, int kk) {
#pragma unroll
    for (int k = 2; k <= 128; k <<= 1) {
#pragma unroll
        for (int j = k >> 1; j >= 1; j >>= 1) {
            if (j == 64) {
                float a = fmaxf(x0, x1), b = fminf(x0, x1);
                x0 = a; x1 = b;
            } else {
                bool lower = (lane & j) == 0;
                bool d0 = ((lane & k) == 0);
                bool d1 = (((lane + 64) & k) == 0);
                float o0 = __shfl_xor(x0, j, 64);
                float o1 = __shfl_xor(x1, j, 64);
                x0 = (lower == d0) ? fmaxf(x0, o0) : fminf(x0, o0);
                x1 = (lower == d1) ? fmaxf(x1, o1) : fminf(x1, o1);
            }
        }
    }
    return (lane < kk ? x0 : 0.f) + (lane + 64 < kk ? x1 : 0.f);
}

#define SL1(d) (fabsf(d) < 1.f ? 0.5f * (d) * (d) : fabsf(d) - 0.5f)
__device__ inline void pos_loss(const float* locs, size_t r, int p, const float4& P,
                                const RowM& R, float& sl1, float& ang) {
    const float2* L2 = (const float2*)(locs + r * (NP * 6) + p * 6);  // 8B-aligned
    float2 A = L2[0], B = L2[1], C = L2[2];
    float g0 = (R.bx - P.x) / (P.z * 0.1f);
    float g1 = (R.by - P.y) / (P.w * 0.1f);
    float g2 = __logf(R.bw / P.z) * 5.f;
    float g3 = __logf(R.bh / P.w) * 5.f;
    float d0 = A.x - g0, d1 = A.y - g1, d2 = B.x - g2, d3 = B.y - g3;
    sl1 += SL1(d0) + SL1(d1) + SL1(d2) + SL1(d3);
    float a0 = C.x - R.sa, a1 = C.y - R.ca;
    ang += a0 * a0 + a1 * a1;
}

// one 64-thread block per PAIR of rows; cross-row software pipeline, no s_barrier.
__global__ void __launch_bounds__(64) mbloss_main(
    const float* __restrict__ locs, const float* __restrict__ scores,
    const float* __restrict__ target, const float* __restrict__ priors,
    float4* __restrict__ partials) {

    __shared__ float s_sc[2 * ROWF];       // 21000 B -> 7 blocks/CU

    const int lane = threadIdx.x;
    const size_t r0 = (size_t)blockIdx.x * 2;
    const size_t r1 = r0 + 1;

    // ---- priors first (vmem ops 1-2) ----
    const int  p1 = lane + 64;
    const bool v1 = (p1 < NP);
    const float4* pr4 = (const float4*)priors;
    float4 P0 = pr4[lane];
    float4 P1 = v1 ? pr4[p1] : make_float4(0.f, 0.f, 1.f, 1.f);

    // uniform tail elements (scalar path) before the DMAs
    const float* g0 = scores + r0 * ROWF;
    const float* g1 = scores + r1 * ROWF;
    const float e0 = g0[2624];
    const float e1 = g1[2624];
    __builtin_amdgcn_sched_barrier(0);

    // ---- vmem ops 3-13: row0 DMAs; ops 14-24: row1 DMAs ----
#pragma unroll
    for (int it = 0; it < 10; ++it) {
        const int off = it * 256 + lane * 4;
        ald16(g0 + off, s_sc + off);
    }
    ald4(g0 + 2560 + lane, s_sc + 2560 + lane);
#pragma unroll
    for (int it = 0; it < 10; ++it) {
        const int off = it * 256 + lane * 4;
        ald16(g1 + off, s_sc + ROWF + off);
    }
    ald4(g1 + 2560 + lane, s_sc + ROWF + 2560 + lane);
    __builtin_amdgcn_sched_barrier(0);

    // ---- match both rows under the full DMA queue (waits only on priors) ----
    RowM R0, R1;
    match_row(target + r0 * 8, P0, P1, lane, p1, v1, R0);
    match_row(target + r1 * 8, P0, P1, lane, p1, v1, R1);

    // ---- row0 staged (leave row1's 11 DMAs in flight) ----
    WAIT_VM11();
    float c00, c01;
    lse_row(s_sc, e0, lane, p1, v1, R0.pos0 ? R0.lbl : 0, R0.pos1 ? R0.lbl : 0, c00, c01);

    // ---- row1 staged ----
    WAIT_VM0();
    float c10, c11;
    lse_row(s_sc + ROWF, e1, lane, p1, v1, R1.pos0 ? R1.lbl : 0, R1.pos1 ? R1.lbl : 0, c10, c11);

    // ---- losses ----
    float acc_conf = 0.f, acc_sl1 = 0.f, acc_ang = 0.f;
    float acc_np = (R0.pos0 ? 1.f : 0.f) + (R0.pos1 ? 1.f : 0.f) +
                   (R1.pos0 ? 1.f : 0.f) + (R1.pos1 ? 1.f : 0.f);

    if (R0.pos0) { acc_conf += c00; pos_loss(locs, r0, lane, P0, R0, acc_sl1, acc_ang); }
    if (R0.pos1) { acc_conf += c01; pos_loss(locs, r0, p1,   P1, R0, acc_sl1, acc_ang); }
    if (R1.pos0) { acc_conf += c10; pos_loss(locs, r1, lane, P0, R1, acc_sl1, acc_ang); }
    if (R1.pos1) { acc_conf += c11; pos_loss(locs, r1, p1,   P1, R1, acc_sl1, acc_ang); }

    {
        int kk = 3 * R0.npos; if (kk > NP) kk = NP;
        float x0 = R0.pos0 ? 0.f : c00;
        float x1 = v1 ? (R0.pos1 ? 0.f : c01) : -1.f;
        acc_conf += topk_sum(x0, x1, lane, kk);
    }
    {
        int kk = 3 * R1.npos; if (kk > NP) kk = NP;
        float x0 = R1.pos0 ? 0.f : c10;
        float x1 = v1 ? (R1.pos1 ? 0.f : c11) : -1.f;
        acc_conf += topk_sum(x0, x1, lane, kk);
    }

    // ---- wave reduce, one float4 store per block (covers both rows) ----
#pragma unroll
    for (int off = 1; off < 64; off <<= 1) {
        acc_conf += __shfl_xor(acc_conf, off, 64);
        acc_sl1  += __shfl_xor(acc_sl1,  off, 64);
        acc_ang  += __shfl_xor(acc_ang,  off, 64);
        acc_np   += __shfl_xor(acc_np,   off, 64);
    }
    if (lane == 0) partials[blockIdx.x] = make_float4(acc_conf, acc_sl1, acc_ang, acc_np);
}

__global__ void __launch_bounds__(1024) mbloss_fin(const float4* __restrict__ partials,
                                                   int n, float* __restrict__ out) {
    __shared__ float4 red[1024];
    const int tid = threadIdx.x;
    float4 a = make_float4(0.f, 0.f, 0.f, 0.f);
    for (int i = tid; i < n; i += 1024) {
        float4 p = partials[i];
        a.x += p.x; a.y += p.y; a.z += p.z; a.w += p.w;
    }
    red[tid] = a;
    __syncthreads();
    for (int s = 512; s > 0; s >>= 1) {
        if (tid < s) {
            red[tid].x += red[tid + s].x; red[tid].y += red[tid + s].y;
            red[tid].z += red[tid + s].z; red[tid].w += red[tid + s].w;
        }
        __syncthreads();
    }
    if (tid == 0) {
        float npt  = red[0].w;
        float conf = red[0].x / npt;
        float loc  = red[0].y / (npt * 4.f);
        float ang  = 25.f * red[0].z / (npt * 2.f);
        out[0] = conf; out[1] = loc; out[2] = ang; out[3] = conf + loc + ang;
    }
}

extern "C" void kernel_launch(void* const* d_in, const int* in_sizes, int n_in,
                              void* d_out, int out_size, void* d_ws, size_t ws_size,
                              hipStream_t stream) {
    const float* locs   = (const float*)d_in[0];
    const float* scores = (const float*)d_in[1];
    const float* target = (const float*)d_in[2];
    const float* priors = (const float*)d_in[3];
    float* out = (float*)d_out;

    const int batch = in_sizes[2] / 8;   // target is (B,1,8); 16384 (even)
    const int nblk  = batch / 2;

    float4* partials = (float4*)d_ws;    // nblk * 16 B = 128 KB << ws_size

    mbloss_main<<<nblk, 64, 0, stream>>>(locs, scores, target, priors, partials);
    mbloss_fin<<<1, 1024, 0, stream>>>(partials, nblk, out);
}